// Round 1
// 673.877 us; speedup vs baseline: 1.3345x; 1.3345x over previous
//
#include <hip/hip_runtime.h>
#include <stdint.h>

#define N_NODES 50000
#define N_EDGES 800000
#define IN_DIM 512
#define OUT_DIM 512
#define KDIM 1024   // [agg | x]
#define NDIM 1024   // [loc | scale-pre]

typedef __bf16 bf16x8 __attribute__((ext_vector_type(8)));
typedef float f32x4 __attribute__((ext_vector_type(4)));

__device__ __forceinline__ unsigned short f2bf(float f) {
    union { float f; unsigned u; } c; c.f = f;
    unsigned u = c.u;
    u += 0x7fffu + ((u >> 16) & 1u);   // round-to-nearest-even
    return (unsigned short)(u >> 16);
}
__device__ __forceinline__ float bf2f(unsigned short h) {
    union { unsigned u; float f; } c; c.u = ((unsigned)h) << 16;
    return c.f;
}

// ---------------- Phase 1: x -> bf16 ----------------
__global__ void xconv_kernel(const float* __restrict__ x, unsigned short* __restrict__ xb) {
    int i = blockIdx.x * blockDim.x + threadIdx.x;   // unit = 4 floats
    const int n4 = N_NODES * IN_DIM / 4;
    if (i < n4) {
        float4 v = ((const float4*)x)[i];
        ushort4 o;
        o.x = f2bf(v.x); o.y = f2bf(v.y); o.z = f2bf(v.z); o.w = f2bf(v.w);
        ((ushort4*)xb)[i] = o;
    }
}

// ---------------- Phase 2: CSR build ----------------
// NOTE: harness delivers integer inputs as int32 (per contract), NOT int64.
__global__ void count_kernel(const int* __restrict__ ei, int* __restrict__ counts) {
    int i = blockIdx.x * blockDim.x + threadIdx.x;
    if (i < N_EDGES) {
        int dst = ei[N_EDGES + i];
        dst = min(max(dst, 0), N_NODES - 1);   // defensive clamp: fault -> wrong answer
        atomicAdd(&counts[dst], 1);
    }
}

// single-block exclusive scan over N_NODES counts -> offs[N_NODES+1], cursor copy
__global__ void scan_kernel(const int* __restrict__ cnt, int* __restrict__ offs,
                            int* __restrict__ cursor, int n) {
    __shared__ int warp_sums[16];
    __shared__ int s_base;
    int tid = threadIdx.x;
    int lane = tid & 63;
    int w = tid >> 6;
    if (tid == 0) s_base = 0;
    __syncthreads();
    for (int start = 0; start < n; start += 1024) {
        int i = start + tid;
        int v = (i < n) ? cnt[i] : 0;
        int s = v;  // inclusive wave scan
        #pragma unroll
        for (int d = 1; d < 64; d <<= 1) {
            int t = __shfl_up(s, d, 64);
            if (lane >= d) s += t;
        }
        if (lane == 63) warp_sums[w] = s;
        __syncthreads();
        if (w == 0) {
            int ws = (lane < 16) ? warp_sums[lane] : 0;
            #pragma unroll
            for (int d = 1; d < 16; d <<= 1) {
                int t = __shfl_up(ws, d, 64);
                if (lane >= d) ws += t;
            }
            if (lane < 16) warp_sums[lane] = ws;  // inclusive wave totals
        }
        __syncthreads();
        int base = s_base + (w > 0 ? warp_sums[w - 1] : 0);
        int excl = base + s - v;
        if (i < n) { offs[i] = excl; cursor[i] = excl; }
        if (i == n - 1) offs[n] = excl + v;
        __syncthreads();
        if (tid == 0) s_base += warp_sums[15];
        __syncthreads();
    }
}

__global__ void fill_kernel(const int* __restrict__ ei, int* __restrict__ cursor,
                            int* __restrict__ bucket) {
    int i = blockIdx.x * blockDim.x + threadIdx.x;
    if (i < N_EDGES) {
        int src = ei[i];
        int dst = ei[N_EDGES + i];
        src = min(max(src, 0), N_NODES - 1);
        dst = min(max(dst, 0), N_NODES - 1);
        int pos = atomicAdd(&cursor[dst], 1);
        bucket[pos] = src;
    }
}

// ---------------- Phase 3: per-node aggregation (fp32 acc, bf16 out) ----------------
// 4x edge unroll: the serial bucket->gather->add chain becomes 4 independent
// in-flight gathers (L2/L3-latency bound otherwise).
__global__ __launch_bounds__(256) void aggregate_kernel(
    const unsigned short* __restrict__ xb, const int* __restrict__ offs,
    const int* __restrict__ bucket, unsigned short* __restrict__ aggb) {
    int n = blockIdx.x;
    int t = threadIdx.x;   // handles bf16 pair -> dims 2t, 2t+1
    int beg = offs[n], end = offs[n + 1];
    const unsigned* xw = (const unsigned*)xb;
    float ax0 = 0.f, ay0 = 0.f, ax1 = 0.f, ay1 = 0.f;
    float ax2 = 0.f, ay2 = 0.f, ax3 = 0.f, ay3 = 0.f;
    int e = beg;
    for (; e + 4 <= end; e += 4) {
        int s0 = bucket[e + 0];
        int s1 = bucket[e + 1];
        int s2 = bucket[e + 2];
        int s3 = bucket[e + 3];
        unsigned v0 = xw[(size_t)s0 * (IN_DIM / 2) + t];
        unsigned v1 = xw[(size_t)s1 * (IN_DIM / 2) + t];
        unsigned v2 = xw[(size_t)s2 * (IN_DIM / 2) + t];
        unsigned v3 = xw[(size_t)s3 * (IN_DIM / 2) + t];
        ax0 += bf2f((unsigned short)(v0 & 0xffffu)); ay0 += bf2f((unsigned short)(v0 >> 16));
        ax1 += bf2f((unsigned short)(v1 & 0xffffu)); ay1 += bf2f((unsigned short)(v1 >> 16));
        ax2 += bf2f((unsigned short)(v2 & 0xffffu)); ay2 += bf2f((unsigned short)(v2 >> 16));
        ax3 += bf2f((unsigned short)(v3 & 0xffffu)); ay3 += bf2f((unsigned short)(v3 >> 16));
    }
    for (; e < end; ++e) {
        int s = bucket[e];
        unsigned v = xw[(size_t)s * (IN_DIM / 2) + t];
        ax0 += bf2f((unsigned short)(v & 0xffffu));
        ay0 += bf2f((unsigned short)(v >> 16));
    }
    float ax = (ax0 + ax1) + (ax2 + ax3);
    float ay = (ay0 + ay1) + (ay2 + ay3);
    unsigned o = (unsigned)f2bf(ax) | ((unsigned)f2bf(ay) << 16);
    ((unsigned*)aggb)[(size_t)n * (IN_DIM / 2) + t] = o;
}

// ---------------- Phase 4: fuse W = [[Wl1,Wr1],[Wl2,Wr2]] -> bf16 [1024][1024] ----------------
__global__ void wconv_kernel(const float* __restrict__ Wl1, const float* __restrict__ Wr1,
                             const float* __restrict__ Wl2, const float* __restrict__ Wr2,
                             unsigned short* __restrict__ Wb) {
    int i = blockIdx.x * blockDim.x + threadIdx.x;
    if (i < NDIM * KDIM) {
        int n = i >> 10, k = i & 1023;
        const float* src;
        if (n < 512) src = (k < 512) ? Wl1 : Wr1;
        else         src = (k < 512) ? Wl2 : Wr2;
        int nn = n & 511, kk = k & 511;
        Wb[i] = f2bf(src[nn * 512 + kk]);
    }
}

// ---------------- Phase 5: GEMM C = H @ W^T with fused epilogue ----------------
// H row = [aggb row | xb row] (both stride 512), W as Wb [N=1024][K=1024] row-major (B^T form)
// BK=64 (128B LDS rows) + XOR-swizzle (chunk ^= row&7) applied as:
//   linear gload_lds dest + inverse-swizzled GLOBAL source + swizzled ds_read
// (Guideline 21: both-sides-or-neither). Kills the 8-way ds_read_b128 conflict.
#define BM 128
#define BN 128
#define BK 64

__device__ __forceinline__ void async_copy16(const void* g, void* lds) {
    __builtin_amdgcn_global_load_lds((const __attribute__((address_space(1))) void*)g,
                                     (__attribute__((address_space(3))) void*)lds, 16, 0, 0);
}

__global__ __launch_bounds__(256, 2) void gemm_kernel(
    const unsigned short* __restrict__ aggb,   // [M,512] bf16
    const unsigned short* __restrict__ xb,     // [M,512] bf16
    const unsigned short* __restrict__ Wb,     // [1024,1024] bf16
    const float* __restrict__ bl1, const float* __restrict__ bl2,
    float* __restrict__ out) {
    constexpr int M = N_NODES;
    __shared__ unsigned short sA[BM * BK];   // 16 KB
    __shared__ unsigned short sB[BN * BK];   // 16 KB

    // grid = (n-tiles fastest, m-tiles slowest): the 8 blocks sharing an A panel
    // are dispatch-adjacent (one per XCD, W panel stays L2-resident per XCD).
    int n0 = blockIdx.x * BN;
    int m0 = blockIdx.y * BM;
    int tid = threadIdx.x;
    int lane = tid & 63;
    int w = tid >> 6;
    int wm = (w >> 1) * 64, wn = (w & 1) * 64;

    f32x4 acc[4][4] = {};

    int fr = lane & 15, q = lane >> 4;
    // fragment-read swizzled chunk offsets (row&7 == fr&7 since wm,wn,i*16 are mult. of 8)
    int sl0 = ((q ^ (fr & 7)) << 3);        // bf16 offset of logical chunk q   (ksub 0)
    int sl1 = (((q + 4) ^ (fr & 7)) << 3);  // bf16 offset of logical chunk q+4 (ksub 1)

    for (int k0 = 0; k0 < KDIM; k0 += BK) {
        const unsigned short* Asrc;
        int ak;
        if (k0 < 512) { Asrc = aggb; ak = k0; } else { Asrc = xb; ak = k0 - 512; }
        // staging: linear chunk C = iss*256 + tid covers LDS 16B slot C;
        // slot p of row r must hold logical chunk (p ^ (r&7)) -> fetch that from global.
        #pragma unroll
        for (int iss = 0; iss < 4; ++iss) {
            int C = iss * 256 + tid;
            int r = C >> 3, p = C & 7;
            int gr = m0 + r; if (gr >= M) gr = M - 1;
            const unsigned short* g = Asrc + (size_t)gr * 512 + ak + ((p ^ (r & 7)) << 3);
            async_copy16(g, sA + (size_t)(iss * 256 + w * 64) * 8);
        }
        #pragma unroll
        for (int iss = 0; iss < 4; ++iss) {
            int C = iss * 256 + tid;
            int r = C >> 3, p = C & 7;
            const unsigned short* g = Wb + (size_t)(n0 + r) * KDIM + k0 + ((p ^ (r & 7)) << 3);
            async_copy16(g, sB + (size_t)(iss * 256 + w * 64) * 8);
        }
        __syncthreads();

        #pragma unroll
        for (int ksub = 0; ksub < 2; ++ksub) {
            int sl = ksub ? sl1 : sl0;
            bf16x8 af[4], bfg[4];
            #pragma unroll
            for (int i = 0; i < 4; ++i)
                af[i] = *(const bf16x8*)(sA + (wm + i * 16 + fr) * BK + sl);
            #pragma unroll
            for (int j = 0; j < 4; ++j)
                bfg[j] = *(const bf16x8*)(sB + (wn + j * 16 + fr) * BK + sl);
            #pragma unroll
            for (int i = 0; i < 4; ++i)
                #pragma unroll
                for (int j = 0; j < 4; ++j)
                    acc[i][j] = __builtin_amdgcn_mfma_f32_16x16x32_bf16(af[i], bfg[j], acc[i][j], 0, 0, 0);
        }
        __syncthreads();
    }

    // epilogue: C/D layout col = lane&15, row = (lane>>4)*4 + reg
    bool is_scale = (n0 >= 512);                 // BN=128 divides 512, so uniform per block
    const float* bias = is_scale ? bl2 : bl1;
    float* obase = out + (is_scale ? (size_t)N_NODES * OUT_DIM : 0);
    int ncol0 = is_scale ? (n0 - 512) : n0;
    int rq = lane >> 4;
    #pragma unroll
    for (int i = 0; i < 4; ++i) {
        #pragma unroll
        for (int j = 0; j < 4; ++j) {
            int colg = ncol0 + wn + j * 16 + fr;
            float b = bias[colg];
            #pragma unroll
            for (int r = 0; r < 4; ++r) {
                int rowg = m0 + wm + i * 16 + rq * 4 + r;
                if (rowg < M) {
                    float v = acc[i][j][r] + b;
                    float res;
                    if (is_scale) {
                        // fast stable softplus: max(v,0) + log(1 + exp(-|v|))
                        float sp = fmaxf(v, 0.f) + __logf(1.f + __expf(-fabsf(v)));
                        res = fminf(sp + 0.001f, 100.f);
                    } else {
                        res = fminf(fmaxf(v, -100.f), 100.f);
                    }
                    // NT store: 205 MB of C must not evict the 102 MB A panel from L3
                    __builtin_nontemporal_store(res, &obase[(size_t)rowg * OUT_DIM + colg]);
                }
            }
        }
    }
}

extern "C" void kernel_launch(void* const* d_in, const int* in_sizes, int n_in,
                              void* d_out, int out_size, void* d_ws, size_t ws_size,
                              hipStream_t stream) {
    const float* x       = (const float*)d_in[0];
    const int* ei        = (const int*)d_in[1];   // int inputs delivered as int32
    const float* Wl1     = (const float*)d_in[2];
    const float* bl1     = (const float*)d_in[3];
    const float* Wr1     = (const float*)d_in[4];
    const float* Wl2     = (const float*)d_in[5];
    const float* bl2     = (const float*)d_in[6];
    const float* Wr2     = (const float*)d_in[7];
    float* out = (float*)d_out;

    char* ws = (char*)d_ws;
    size_t off = 0;
    auto alloc = [&](size_t bytes) -> void* {
        void* p = ws + off;
        off = (off + bytes + 255) & ~(size_t)255;
        return p;
    };
    unsigned short* xb    = (unsigned short*)alloc((size_t)N_NODES * IN_DIM * 2);  // 51.2 MB
    unsigned short* aggb  = (unsigned short*)alloc((size_t)N_NODES * IN_DIM * 2);  // 51.2 MB
    unsigned short* Wb    = (unsigned short*)alloc((size_t)NDIM * KDIM * 2);       // 2 MB
    int* counts           = (int*)alloc((size_t)(N_NODES + 1) * 4);
    int* offs             = (int*)alloc((size_t)(N_NODES + 1) * 4);
    int* cursor           = (int*)alloc((size_t)N_NODES * 4);
    int* bucket           = (int*)alloc((size_t)N_EDGES * 4);                      // 3.2 MB

    hipMemsetAsync(counts, 0, (size_t)(N_NODES + 1) * 4, stream);

    xconv_kernel<<<(N_NODES * IN_DIM / 4 + 255) / 256, 256, 0, stream>>>(x, xb);
    count_kernel<<<(N_EDGES + 255) / 256, 256, 0, stream>>>(ei, counts);
    scan_kernel<<<1, 1024, 0, stream>>>(counts, offs, cursor, N_NODES);
    fill_kernel<<<(N_EDGES + 255) / 256, 256, 0, stream>>>(ei, cursor, bucket);
    aggregate_kernel<<<N_NODES, 256, 0, stream>>>(xb, offs, bucket, aggb);
    wconv_kernel<<<(NDIM * KDIM + 255) / 256, 256, 0, stream>>>(Wl1, Wr1, Wl2, Wr2, Wb);

    dim3 g(NDIM / BN, (N_NODES + BM - 1) / BM);
    gemm_kernel<<<g, 256, 0, stream>>>(aggb, xb, Wb, bl1, bl2, out);
}

// Round 2
// 647.842 us; speedup vs baseline: 1.3881x; 1.0402x over previous
//
#include <hip/hip_runtime.h>
#include <stdint.h>

#define N_NODES 50000
#define N_EDGES 800000
#define IN_DIM 512
#define OUT_DIM 512
#define KDIM 1024   // [agg | x]
#define NDIM 1024   // [loc | scale-pre]

typedef __bf16 bf16x8 __attribute__((ext_vector_type(8)));
typedef float f32x4 __attribute__((ext_vector_type(4)));

__device__ __forceinline__ unsigned short f2bf(float f) {
    union { float f; unsigned u; } c; c.f = f;
    unsigned u = c.u;
    u += 0x7fffu + ((u >> 16) & 1u);   // round-to-nearest-even
    return (unsigned short)(u >> 16);
}
__device__ __forceinline__ float bf2f(unsigned short h) {
    union { unsigned u; float f; } c; c.u = ((unsigned)h) << 16;
    return c.f;
}

// ---------------- Phase 1: x -> bf16 ----------------
__global__ void xconv_kernel(const float* __restrict__ x, unsigned short* __restrict__ xb) {
    int i = blockIdx.x * blockDim.x + threadIdx.x;   // unit = 4 floats
    const int n4 = N_NODES * IN_DIM / 4;
    if (i < n4) {
        float4 v = ((const float4*)x)[i];
        ushort4 o;
        o.x = f2bf(v.x); o.y = f2bf(v.y); o.z = f2bf(v.z); o.w = f2bf(v.w);
        ((ushort4*)xb)[i] = o;
    }
}

// ---------------- Phase 2: CSR build ----------------
// NOTE: harness delivers integer inputs as int32 (per contract), NOT int64.
__global__ void count_kernel(const int* __restrict__ ei, int* __restrict__ counts) {
    int i = blockIdx.x * blockDim.x + threadIdx.x;
    if (i < N_EDGES) {
        int dst = ei[N_EDGES + i];
        dst = min(max(dst, 0), N_NODES - 1);   // defensive clamp: fault -> wrong answer
        atomicAdd(&counts[dst], 1);
    }
}

// Multi-block scan (replaces the serial single-block/single-CU version):
// s1: per-1024-block exclusive scan + block totals
__global__ __launch_bounds__(1024) void scan_local_kernel(
    const int* __restrict__ cnt, int* __restrict__ offs,
    int* __restrict__ bsums, int n) {
    __shared__ int warp_sums[16];
    int tid = threadIdx.x;
    int lane = tid & 63;
    int w = tid >> 6;
    int i = blockIdx.x * 1024 + tid;
    int v = (i < n) ? cnt[i] : 0;
    int s = v;  // inclusive wave scan
    #pragma unroll
    for (int d = 1; d < 64; d <<= 1) {
        int t = __shfl_up(s, d, 64);
        if (lane >= d) s += t;
    }
    if (lane == 63) warp_sums[w] = s;
    __syncthreads();
    if (w == 0) {
        int ws = (lane < 16) ? warp_sums[lane] : 0;
        #pragma unroll
        for (int d = 1; d < 16; d <<= 1) {
            int t = __shfl_up(ws, d, 64);
            if (lane >= d) ws += t;
        }
        if (lane < 16) warp_sums[lane] = ws;  // inclusive wave totals
    }
    __syncthreads();
    int base = (w > 0 ? warp_sums[w - 1] : 0);
    if (i < n) offs[i] = base + s - v;        // block-local exclusive
    if (tid == 1023) bsums[blockIdx.x] = base + s;   // block total
}

// s2: one wave scans the (<=64) block sums -> exclusive bases in-place
__global__ void scan_bsums_kernel(int* __restrict__ bsums, int nb) {
    int lane = threadIdx.x & 63;
    int v = (lane < nb) ? bsums[lane] : 0;
    int s = v;
    #pragma unroll
    for (int d = 1; d < 64; d <<= 1) {
        int t = __shfl_up(s, d, 64);
        if (lane >= d) s += t;
    }
    if (lane < nb) bsums[lane] = s - v;
}

// s3: add block base, copy cursor, write offs[n]
__global__ __launch_bounds__(1024) void scan_apply_kernel(
    int* __restrict__ offs, int* __restrict__ cursor,
    const int* __restrict__ bsums, const int* __restrict__ cnt, int n) {
    int i = blockIdx.x * 1024 + threadIdx.x;
    if (i < n) {
        int o = offs[i] + bsums[blockIdx.x];
        offs[i] = o;
        cursor[i] = o;
        if (i == n - 1) offs[n] = o + cnt[i];
    }
}

__global__ void fill_kernel(const int* __restrict__ ei, int* __restrict__ cursor,
                            int* __restrict__ bucket) {
    int i = blockIdx.x * blockDim.x + threadIdx.x;
    if (i < N_EDGES) {
        int src = ei[i];
        int dst = ei[N_EDGES + i];
        src = min(max(src, 0), N_NODES - 1);
        dst = min(max(dst, 0), N_NODES - 1);
        int pos = atomicAdd(&cursor[dst], 1);
        bucket[pos] = src;
    }
}

// ---------------- Phase 3: per-node aggregation (fp32 acc, bf16 out) ----------------
// 8x edge unroll: 8 independent in-flight row-gathers per wave (L3-latency bound).
__global__ __launch_bounds__(256) void aggregate_kernel(
    const unsigned short* __restrict__ xb, const int* __restrict__ offs,
    const int* __restrict__ bucket, unsigned short* __restrict__ aggb) {
    int n = blockIdx.x;
    int t = threadIdx.x;   // handles bf16 pair -> dims 2t, 2t+1
    int beg = offs[n], end = offs[n + 1];
    const unsigned* xw = (const unsigned*)xb;
    float ax[8] = {}, ay[8] = {};
    int e = beg;
    for (; e + 8 <= end; e += 8) {
        int idx[8];
        unsigned v[8];
        #pragma unroll
        for (int u = 0; u < 8; ++u) idx[u] = bucket[e + u];
        #pragma unroll
        for (int u = 0; u < 8; ++u) v[u] = xw[(size_t)idx[u] * (IN_DIM / 2) + t];
        #pragma unroll
        for (int u = 0; u < 8; ++u) {
            ax[u] += bf2f((unsigned short)(v[u] & 0xffffu));
            ay[u] += bf2f((unsigned short)(v[u] >> 16));
        }
    }
    for (; e < end; ++e) {
        int s = bucket[e];
        unsigned v = xw[(size_t)s * (IN_DIM / 2) + t];
        ax[0] += bf2f((unsigned short)(v & 0xffffu));
        ay[0] += bf2f((unsigned short)(v >> 16));
    }
    float sx = ((ax[0] + ax[1]) + (ax[2] + ax[3])) + ((ax[4] + ax[5]) + (ax[6] + ax[7]));
    float sy = ((ay[0] + ay[1]) + (ay[2] + ay[3])) + ((ay[4] + ay[5]) + (ay[6] + ay[7]));
    unsigned o = (unsigned)f2bf(sx) | ((unsigned)f2bf(sy) << 16);
    ((unsigned*)aggb)[(size_t)n * (IN_DIM / 2) + t] = o;
}

// ---------------- Phase 4: fuse W = [[Wl1,Wr1],[Wl2,Wr2]] -> bf16 [1024][1024] ----------------
__global__ void wconv_kernel(const float* __restrict__ Wl1, const float* __restrict__ Wr1,
                             const float* __restrict__ Wl2, const float* __restrict__ Wr2,
                             unsigned short* __restrict__ Wb) {
    int i = blockIdx.x * blockDim.x + threadIdx.x;
    if (i < NDIM * KDIM) {
        int n = i >> 10, k = i & 1023;
        const float* src;
        if (n < 512) src = (k < 512) ? Wl1 : Wr1;
        else         src = (k < 512) ? Wl2 : Wr2;
        int nn = n & 511, kk = k & 511;
        Wb[i] = f2bf(src[nn * 512 + kk]);
    }
}

// ---------------- Phase 5: GEMM C = H @ W^T with fused epilogue ----------------
// H row = [aggb row | xb row] (both stride 512), W as Wb [N=1024][K=1024] row-major (B^T form)
// BM=128, BN=256 (wave tile 64x128, acc[4][8]): 64 MFMA per K-step vs 24 ds_reads,
// and each A panel is shared by only 4 n-blocks (halves A re-fetch).
// BK=64 (128B LDS rows) + XOR-swizzle (chunk ^= row&7) as inverse-swizzled global
// source + swizzled ds_read (Guideline 21).
#define BM 128
#define BN 256
#define BK 64

__device__ __forceinline__ void async_copy16(const void* g, void* lds) {
    __builtin_amdgcn_global_load_lds((const __attribute__((address_space(1))) void*)g,
                                     (__attribute__((address_space(3))) void*)lds, 16, 0, 0);
}

__global__ __launch_bounds__(256, 2) void gemm_kernel(
    const unsigned short* __restrict__ aggb,   // [M,512] bf16
    const unsigned short* __restrict__ xb,     // [M,512] bf16
    const unsigned short* __restrict__ Wb,     // [1024,1024] bf16
    const float* __restrict__ bl1, const float* __restrict__ bl2,
    float* __restrict__ out) {
    constexpr int M = N_NODES;
    __shared__ unsigned short sA[BM * BK];   // 16 KB
    __shared__ unsigned short sB[BN * BK];   // 32 KB

    int n0 = blockIdx.x * BN;   // 0,256,512,768
    int m0 = blockIdx.y * BM;
    int tid = threadIdx.x;
    int lane = tid & 63;
    int w = tid >> 6;
    int wm = (w >> 1) * 64, wn = (w & 1) * 128;

    f32x4 acc[4][8] = {};

    int fr = lane & 15, q = lane >> 4;
    // fragment-read swizzled chunk offsets (row&7 == fr&7: wm,wn,i*16 are mult. of 8)
    int sl0 = ((q ^ (fr & 7)) << 3);        // bf16 offset of logical chunk q   (ksub 0)
    int sl1 = (((q + 4) ^ (fr & 7)) << 3);  // bf16 offset of logical chunk q+4 (ksub 1)

    for (int k0 = 0; k0 < KDIM; k0 += BK) {
        const unsigned short* Asrc;
        int ak;
        if (k0 < 512) { Asrc = aggb; ak = k0; } else { Asrc = xb; ak = k0 - 512; }
        // staging: linear chunk C = iss*256 + tid -> LDS 16B slot C;
        // slot p of row r must hold logical chunk (p ^ (r&7)) -> fetch that from global.
        #pragma unroll
        for (int iss = 0; iss < 4; ++iss) {
            int C = iss * 256 + tid;
            int r = C >> 3, p = C & 7;
            int gr = m0 + r; if (gr >= M) gr = M - 1;
            const unsigned short* g = Asrc + (size_t)gr * 512 + ak + ((p ^ (r & 7)) << 3);
            async_copy16(g, sA + (size_t)(iss * 256 + w * 64) * 8);
        }
        #pragma unroll
        for (int iss = 0; iss < 8; ++iss) {
            int C = iss * 256 + tid;
            int r = C >> 3, p = C & 7;
            const unsigned short* g = Wb + (size_t)(n0 + r) * KDIM + k0 + ((p ^ (r & 7)) << 3);
            async_copy16(g, sB + (size_t)(iss * 256 + w * 64) * 8);
        }
        __syncthreads();

        #pragma unroll
        for (int ksub = 0; ksub < 2; ++ksub) {
            int sl = ksub ? sl1 : sl0;
            bf16x8 af[4], bfg[8];
            #pragma unroll
            for (int i = 0; i < 4; ++i)
                af[i] = *(const bf16x8*)(sA + (wm + i * 16 + fr) * BK + sl);
            #pragma unroll
            for (int j = 0; j < 8; ++j)
                bfg[j] = *(const bf16x8*)(sB + (wn + j * 16 + fr) * BK + sl);
            #pragma unroll
            for (int i = 0; i < 4; ++i)
                #pragma unroll
                for (int j = 0; j < 8; ++j)
                    acc[i][j] = __builtin_amdgcn_mfma_f32_16x16x32_bf16(af[i], bfg[j], acc[i][j], 0, 0, 0);
        }
        __syncthreads();
    }

    // epilogue: C/D layout col = lane&15, row = (lane>>4)*4 + reg
    bool is_scale = (n0 >= 512);                 // BN=256 divides 512, so uniform per block
    const float* bias = is_scale ? bl2 : bl1;
    float* obase = out + (is_scale ? (size_t)N_NODES * OUT_DIM : 0);
    int ncol0 = is_scale ? (n0 - 512) : n0;
    int rq = lane >> 4;
    #pragma unroll
    for (int i = 0; i < 4; ++i) {
        #pragma unroll
        for (int j = 0; j < 8; ++j) {
            int colg = ncol0 + wn + j * 16 + fr;
            float b = bias[colg];
            #pragma unroll
            for (int r = 0; r < 4; ++r) {
                int rowg = m0 + wm + i * 16 + rq * 4 + r;
                if (rowg < M) {
                    float v = acc[i][j][r] + b;
                    float res;
                    if (is_scale) {
                        // fast stable softplus: max(v,0) + log(1 + exp(-|v|))
                        float sp = fmaxf(v, 0.f) + __logf(1.f + __expf(-fabsf(v)));
                        res = fminf(sp + 0.001f, 100.f);
                    } else {
                        res = fminf(fmaxf(v, -100.f), 100.f);
                    }
                    // NT store: 205 MB of C must not evict the A panels from L3
                    __builtin_nontemporal_store(res, &obase[(size_t)rowg * OUT_DIM + colg]);
                }
            }
        }
    }
}

extern "C" void kernel_launch(void* const* d_in, const int* in_sizes, int n_in,
                              void* d_out, int out_size, void* d_ws, size_t ws_size,
                              hipStream_t stream) {
    const float* x       = (const float*)d_in[0];
    const int* ei        = (const int*)d_in[1];   // int inputs delivered as int32
    const float* Wl1     = (const float*)d_in[2];
    const float* bl1     = (const float*)d_in[3];
    const float* Wr1     = (const float*)d_in[4];
    const float* Wl2     = (const float*)d_in[5];
    const float* bl2     = (const float*)d_in[6];
    const float* Wr2     = (const float*)d_in[7];
    float* out = (float*)d_out;

    char* ws = (char*)d_ws;
    size_t off = 0;
    auto alloc = [&](size_t bytes) -> void* {
        void* p = ws + off;
        off = (off + bytes + 255) & ~(size_t)255;
        return p;
    };
    unsigned short* xb    = (unsigned short*)alloc((size_t)N_NODES * IN_DIM * 2);  // 51.2 MB
    unsigned short* aggb  = (unsigned short*)alloc((size_t)N_NODES * IN_DIM * 2);  // 51.2 MB
    unsigned short* Wb    = (unsigned short*)alloc((size_t)NDIM * KDIM * 2);       // 2 MB
    int* counts           = (int*)alloc((size_t)(N_NODES + 1) * 4);
    int* offs             = (int*)alloc((size_t)(N_NODES + 1) * 4);
    int* cursor           = (int*)alloc((size_t)N_NODES * 4);
    int* bucket           = (int*)alloc((size_t)N_EDGES * 4);                      // 3.2 MB
    int* bsums            = (int*)alloc(64 * 4);

    hipMemsetAsync(counts, 0, (size_t)(N_NODES + 1) * 4, stream);

    const int nb = (N_NODES + 1023) / 1024;   // 49

    xconv_kernel<<<(N_NODES * IN_DIM / 4 + 255) / 256, 256, 0, stream>>>(x, xb);
    count_kernel<<<(N_EDGES + 255) / 256, 256, 0, stream>>>(ei, counts);
    scan_local_kernel<<<nb, 1024, 0, stream>>>(counts, offs, bsums, N_NODES);
    scan_bsums_kernel<<<1, 64, 0, stream>>>(bsums, nb);
    scan_apply_kernel<<<nb, 1024, 0, stream>>>(offs, cursor, bsums, counts, N_NODES);
    fill_kernel<<<(N_EDGES + 255) / 256, 256, 0, stream>>>(ei, cursor, bucket);
    aggregate_kernel<<<N_NODES, 256, 0, stream>>>(xb, offs, bucket, aggb);
    wconv_kernel<<<(NDIM * KDIM + 255) / 256, 256, 0, stream>>>(Wl1, Wr1, Wl2, Wr2, Wb);

    dim3 g(NDIM / BN, (N_NODES + BM - 1) / BM);
    gemm_kernel<<<g, 256, 0, stream>>>(aggb, xb, Wb, bl1, bl2, out);
}

// Round 3
// 599.957 us; speedup vs baseline: 1.4989x; 1.0798x over previous
//
#include <hip/hip_runtime.h>
#include <stdint.h>

#define N_NODES 50000
#define N_EDGES 800000
#define IN_DIM 512
#define OUT_DIM 512
#define KDIM 1024   // [agg | x]
#define NDIM 1024   // [loc | scale-pre]

typedef __bf16 bf16x8 __attribute__((ext_vector_type(8)));
typedef float f32x4 __attribute__((ext_vector_type(4)));

__device__ __forceinline__ unsigned short f2bf(float f) {
    union { float f; unsigned u; } c; c.f = f;
    unsigned u = c.u;
    u += 0x7fffu + ((u >> 16) & 1u);   // round-to-nearest-even
    return (unsigned short)(u >> 16);
}
__device__ __forceinline__ float bf2f(unsigned short h) {
    union { unsigned u; float f; } c; c.u = ((unsigned)h) << 16;
    return c.f;
}

// ---------------- Phase 1: x -> bf16 ----------------
__global__ void xconv_kernel(const float* __restrict__ x, unsigned short* __restrict__ xb) {
    int i = blockIdx.x * blockDim.x + threadIdx.x;   // unit = 4 floats
    const int n4 = N_NODES * IN_DIM / 4;
    if (i < n4) {
        float4 v = ((const float4*)x)[i];
        ushort4 o;
        o.x = f2bf(v.x); o.y = f2bf(v.y); o.z = f2bf(v.z); o.w = f2bf(v.w);
        ((ushort4*)xb)[i] = o;
    }
}

// ---------------- Phase 2: CSR build ----------------
// NOTE: harness delivers integer inputs as int32 (per contract), NOT int64.
__global__ void count_kernel(const int* __restrict__ ei, int* __restrict__ counts) {
    int i = blockIdx.x * blockDim.x + threadIdx.x;
    if (i < N_EDGES) {
        int dst = ei[N_EDGES + i];
        dst = min(max(dst, 0), N_NODES - 1);   // defensive clamp: fault -> wrong answer
        atomicAdd(&counts[dst], 1);
    }
}

// Multi-block scan: s1 per-1024-block exclusive scan + block totals
__global__ __launch_bounds__(1024) void scan_local_kernel(
    const int* __restrict__ cnt, int* __restrict__ offs,
    int* __restrict__ bsums, int n) {
    __shared__ int warp_sums[16];
    int tid = threadIdx.x;
    int lane = tid & 63;
    int w = tid >> 6;
    int i = blockIdx.x * 1024 + tid;
    int v = (i < n) ? cnt[i] : 0;
    int s = v;  // inclusive wave scan
    #pragma unroll
    for (int d = 1; d < 64; d <<= 1) {
        int t = __shfl_up(s, d, 64);
        if (lane >= d) s += t;
    }
    if (lane == 63) warp_sums[w] = s;
    __syncthreads();
    if (w == 0) {
        int ws = (lane < 16) ? warp_sums[lane] : 0;
        #pragma unroll
        for (int d = 1; d < 16; d <<= 1) {
            int t = __shfl_up(ws, d, 64);
            if (lane >= d) ws += t;
        }
        if (lane < 16) warp_sums[lane] = ws;  // inclusive wave totals
    }
    __syncthreads();
    int base = (w > 0 ? warp_sums[w - 1] : 0);
    if (i < n) offs[i] = base + s - v;        // block-local exclusive
    if (tid == 1023) bsums[blockIdx.x] = base + s;   // block total
}

// s2: one wave scans the (<=64) block sums -> exclusive bases in-place
__global__ void scan_bsums_kernel(int* __restrict__ bsums, int nb) {
    int lane = threadIdx.x & 63;
    int v = (lane < nb) ? bsums[lane] : 0;
    int s = v;
    #pragma unroll
    for (int d = 1; d < 64; d <<= 1) {
        int t = __shfl_up(s, d, 64);
        if (lane >= d) s += t;
    }
    if (lane < nb) bsums[lane] = s - v;
}

// s3: add block base, copy cursor, write offs[n]
__global__ __launch_bounds__(1024) void scan_apply_kernel(
    int* __restrict__ offs, int* __restrict__ cursor,
    const int* __restrict__ bsums, const int* __restrict__ cnt, int n) {
    int i = blockIdx.x * 1024 + threadIdx.x;
    if (i < n) {
        int o = offs[i] + bsums[blockIdx.x];
        offs[i] = o;
        cursor[i] = o;
        if (i == n - 1) offs[n] = o + cnt[i];
    }
}

__global__ void fill_kernel(const int* __restrict__ ei, int* __restrict__ cursor,
                            int* __restrict__ bucket) {
    int i = blockIdx.x * blockDim.x + threadIdx.x;
    if (i < N_EDGES) {
        int src = ei[i];
        int dst = ei[N_EDGES + i];
        src = min(max(src, 0), N_NODES - 1);
        dst = min(max(dst, 0), N_NODES - 1);
        int pos = atomicAdd(&cursor[dst], 1);
        bucket[pos] = src;
    }
}

// ---------------- Phase 3: per-node aggregation (fp32 acc, bf16 out) ----------------
// 1 wave per node: 64 lanes x 16B (uint4 = 8 bf16) = full 1KB row per load instr.
// 4 nodes per 256-thread block; 4-edge unroll -> 4x16B outstanding per lane.
__global__ __launch_bounds__(256) void aggregate_kernel(
    const unsigned short* __restrict__ xb, const int* __restrict__ offs,
    const int* __restrict__ bucket, unsigned short* __restrict__ aggb) {
    int wid = threadIdx.x >> 6;
    int lane = threadIdx.x & 63;
    int n = blockIdx.x * 4 + wid;
    if (n >= N_NODES) return;
    int beg = offs[n], end = offs[n + 1];
    // two accumulator sets to break per-slot dependency chains
    float a0[8] = {}, a1[8] = {};
    int e = beg;
    for (; e + 4 <= end; e += 4) {
        int s0 = bucket[e + 0];
        int s1 = bucket[e + 1];
        int s2 = bucket[e + 2];
        int s3 = bucket[e + 3];
        uint4 v0 = *(const uint4*)(xb + (size_t)s0 * IN_DIM + lane * 8);
        uint4 v1 = *(const uint4*)(xb + (size_t)s1 * IN_DIM + lane * 8);
        uint4 v2 = *(const uint4*)(xb + (size_t)s2 * IN_DIM + lane * 8);
        uint4 v3 = *(const uint4*)(xb + (size_t)s3 * IN_DIM + lane * 8);
        a0[0] += bf2f((unsigned short)(v0.x & 0xffffu)); a0[1] += bf2f((unsigned short)(v0.x >> 16));
        a0[2] += bf2f((unsigned short)(v0.y & 0xffffu)); a0[3] += bf2f((unsigned short)(v0.y >> 16));
        a0[4] += bf2f((unsigned short)(v0.z & 0xffffu)); a0[5] += bf2f((unsigned short)(v0.z >> 16));
        a0[6] += bf2f((unsigned short)(v0.w & 0xffffu)); a0[7] += bf2f((unsigned short)(v0.w >> 16));
        a1[0] += bf2f((unsigned short)(v1.x & 0xffffu)); a1[1] += bf2f((unsigned short)(v1.x >> 16));
        a1[2] += bf2f((unsigned short)(v1.y & 0xffffu)); a1[3] += bf2f((unsigned short)(v1.y >> 16));
        a1[4] += bf2f((unsigned short)(v1.z & 0xffffu)); a1[5] += bf2f((unsigned short)(v1.z >> 16));
        a1[6] += bf2f((unsigned short)(v1.w & 0xffffu)); a1[7] += bf2f((unsigned short)(v1.w >> 16));
        a0[0] += bf2f((unsigned short)(v2.x & 0xffffu)); a0[1] += bf2f((unsigned short)(v2.x >> 16));
        a0[2] += bf2f((unsigned short)(v2.y & 0xffffu)); a0[3] += bf2f((unsigned short)(v2.y >> 16));
        a0[4] += bf2f((unsigned short)(v2.z & 0xffffu)); a0[5] += bf2f((unsigned short)(v2.z >> 16));
        a0[6] += bf2f((unsigned short)(v2.w & 0xffffu)); a0[7] += bf2f((unsigned short)(v2.w >> 16));
        a1[0] += bf2f((unsigned short)(v3.x & 0xffffu)); a1[1] += bf2f((unsigned short)(v3.x >> 16));
        a1[2] += bf2f((unsigned short)(v3.y & 0xffffu)); a1[3] += bf2f((unsigned short)(v3.y >> 16));
        a1[4] += bf2f((unsigned short)(v3.z & 0xffffu)); a1[5] += bf2f((unsigned short)(v3.z >> 16));
        a1[6] += bf2f((unsigned short)(v3.w & 0xffffu)); a1[7] += bf2f((unsigned short)(v3.w >> 16));
    }
    for (; e < end; ++e) {
        int s = bucket[e];
        uint4 v = *(const uint4*)(xb + (size_t)s * IN_DIM + lane * 8);
        a0[0] += bf2f((unsigned short)(v.x & 0xffffu)); a0[1] += bf2f((unsigned short)(v.x >> 16));
        a0[2] += bf2f((unsigned short)(v.y & 0xffffu)); a0[3] += bf2f((unsigned short)(v.y >> 16));
        a0[4] += bf2f((unsigned short)(v.z & 0xffffu)); a0[5] += bf2f((unsigned short)(v.z >> 16));
        a0[6] += bf2f((unsigned short)(v.w & 0xffffu)); a0[7] += bf2f((unsigned short)(v.w >> 16));
    }
    uint4 o;
    o.x = (unsigned)f2bf(a0[0] + a1[0]) | ((unsigned)f2bf(a0[1] + a1[1]) << 16);
    o.y = (unsigned)f2bf(a0[2] + a1[2]) | ((unsigned)f2bf(a0[3] + a1[3]) << 16);
    o.z = (unsigned)f2bf(a0[4] + a1[4]) | ((unsigned)f2bf(a0[5] + a1[5]) << 16);
    o.w = (unsigned)f2bf(a0[6] + a1[6]) | ((unsigned)f2bf(a0[7] + a1[7]) << 16);
    *(uint4*)(aggb + (size_t)n * IN_DIM + lane * 8) = o;
}

// ---------------- Phase 4: fuse W = [[Wl1,Wr1],[Wl2,Wr2]] -> bf16 [1024][1024] ----------------
__global__ void wconv_kernel(const float* __restrict__ Wl1, const float* __restrict__ Wr1,
                             const float* __restrict__ Wl2, const float* __restrict__ Wr2,
                             unsigned short* __restrict__ Wb) {
    int i = blockIdx.x * blockDim.x + threadIdx.x;
    if (i < NDIM * KDIM) {
        int n = i >> 10, k = i & 1023;
        const float* src;
        if (n < 512) src = (k < 512) ? Wl1 : Wr1;
        else         src = (k < 512) ? Wl2 : Wr2;
        int nn = n & 511, kk = k & 511;
        Wb[i] = f2bf(src[nn * 512 + kk]);
    }
}

// ---------------- Phase 5: GEMM C = H @ W^T with fused epilogue ----------------
// Round-1 geometry (BM=BN=128, BK=64, VGPR 64, 32KB LDS, ~3 blocks/CU) + co-XCD
// swizzle: each XCD owns a contiguous logical chunk (n-fastest within chunk), so
// the 8 blocks sharing an A panel run on ONE XCD back-to-back (A fetched ~once
// per L2) and W (2MB) stays L2-resident per XCD.
// BK=64 XOR-swizzle (chunk ^= row&7) as inverse-swizzled global source +
// swizzled ds_read (Guideline 21) -> 0 bank conflicts.
#define BM 128
#define BN 128
#define BK 64
#define NT_TILES (NDIM / BN)                       // 8
#define MT_TILES ((N_NODES + BM - 1) / BM)         // 391
#define NWG (NT_TILES * MT_TILES)                  // 3128 = 8 * 391

__device__ __forceinline__ void async_copy16(const void* g, void* lds) {
    __builtin_amdgcn_global_load_lds((const __attribute__((address_space(1))) void*)g,
                                     (__attribute__((address_space(3))) void*)lds, 16, 0, 0);
}

__global__ __launch_bounds__(256, 2) void gemm_kernel(
    const unsigned short* __restrict__ aggb,   // [M,512] bf16
    const unsigned short* __restrict__ xb,     // [M,512] bf16
    const unsigned short* __restrict__ Wb,     // [1024,1024] bf16
    const float* __restrict__ bl1, const float* __restrict__ bl2,
    float* __restrict__ out) {
    constexpr int M = N_NODES;
    __shared__ unsigned short sA[BM * BK];   // 16 KB
    __shared__ unsigned short sB[BN * BK];   // 16 KB

    // co-XCD chunk swizzle: physical bid -> xcd = bid&7, slot = bid>>3;
    // logical = xcd*391 + slot keeps each m-row's 8 n-tiles on one XCD.
    int bid = blockIdx.x;
    int logical = (bid & 7) * (NWG / 8) + (bid >> 3);
    int nt = logical & (NT_TILES - 1);
    int mt = logical >> 3;
    int n0 = nt * BN;
    int m0 = mt * BM;

    int tid = threadIdx.x;
    int lane = tid & 63;
    int w = tid >> 6;
    int wm = (w >> 1) * 64, wn = (w & 1) * 64;

    f32x4 acc[4][4] = {};

    int fr = lane & 15, q = lane >> 4;
    // fragment-read swizzled chunk offsets (row&7 == fr&7 since wm,wn,i*16 are mult. of 8)
    int sl0 = ((q ^ (fr & 7)) << 3);        // bf16 offset of logical chunk q   (ksub 0)
    int sl1 = (((q + 4) ^ (fr & 7)) << 3);  // bf16 offset of logical chunk q+4 (ksub 1)

    for (int k0 = 0; k0 < KDIM; k0 += BK) {
        const unsigned short* Asrc;
        int ak;
        if (k0 < 512) { Asrc = aggb; ak = k0; } else { Asrc = xb; ak = k0 - 512; }
        // staging: linear chunk C = iss*256 + tid -> LDS 16B slot C;
        // slot p of row r must hold logical chunk (p ^ (r&7)) -> fetch that from global.
        #pragma unroll
        for (int iss = 0; iss < 4; ++iss) {
            int C = iss * 256 + tid;
            int r = C >> 3, p = C & 7;
            int gr = m0 + r; if (gr >= M) gr = M - 1;
            const unsigned short* g = Asrc + (size_t)gr * 512 + ak + ((p ^ (r & 7)) << 3);
            async_copy16(g, sA + (size_t)(iss * 256 + w * 64) * 8);
        }
        #pragma unroll
        for (int iss = 0; iss < 4; ++iss) {
            int C = iss * 256 + tid;
            int r = C >> 3, p = C & 7;
            const unsigned short* g = Wb + (size_t)(n0 + r) * KDIM + k0 + ((p ^ (r & 7)) << 3);
            async_copy16(g, sB + (size_t)(iss * 256 + w * 64) * 8);
        }
        __syncthreads();

        #pragma unroll
        for (int ksub = 0; ksub < 2; ++ksub) {
            int sl = ksub ? sl1 : sl0;
            bf16x8 af[4], bfg[4];
            #pragma unroll
            for (int i = 0; i < 4; ++i)
                af[i] = *(const bf16x8*)(sA + (wm + i * 16 + fr) * BK + sl);
            #pragma unroll
            for (int j = 0; j < 4; ++j)
                bfg[j] = *(const bf16x8*)(sB + (wn + j * 16 + fr) * BK + sl);
            #pragma unroll
            for (int i = 0; i < 4; ++i)
                #pragma unroll
                for (int j = 0; j < 4; ++j)
                    acc[i][j] = __builtin_amdgcn_mfma_f32_16x16x32_bf16(af[i], bfg[j], acc[i][j], 0, 0, 0);
        }
        __syncthreads();
    }

    // epilogue: C/D layout col = lane&15, row = (lane>>4)*4 + reg
    bool is_scale = (n0 >= 512);                 // BN=128 divides 512, so uniform per block
    const float* bias = is_scale ? bl2 : bl1;
    float* obase = out + (is_scale ? (size_t)N_NODES * OUT_DIM : 0);
    int ncol0 = is_scale ? (n0 - 512) : n0;
    int rq = lane >> 4;
    #pragma unroll
    for (int i = 0; i < 4; ++i) {
        #pragma unroll
        for (int j = 0; j < 4; ++j) {
            int colg = ncol0 + wn + j * 16 + fr;
            float b = bias[colg];
            #pragma unroll
            for (int r = 0; r < 4; ++r) {
                int rowg = m0 + wm + i * 16 + rq * 4 + r;
                if (rowg < M) {
                    float v = acc[i][j][r] + b;
                    float res;
                    if (is_scale) {
                        // fast stable softplus: max(v,0) + log(1 + exp(-|v|))
                        float sp = fmaxf(v, 0.f) + __logf(1.f + __expf(-fabsf(v)));
                        res = fminf(sp + 0.001f, 100.f);
                    } else {
                        res = fminf(fmaxf(v, -100.f), 100.f);
                    }
                    // NT store: 205 MB of C must not evict the A panels from L3
                    __builtin_nontemporal_store(res, &obase[(size_t)rowg * OUT_DIM + colg]);
                }
            }
        }
    }
}

extern "C" void kernel_launch(void* const* d_in, const int* in_sizes, int n_in,
                              void* d_out, int out_size, void* d_ws, size_t ws_size,
                              hipStream_t stream) {
    const float* x       = (const float*)d_in[0];
    const int* ei        = (const int*)d_in[1];   // int inputs delivered as int32
    const float* Wl1     = (const float*)d_in[2];
    const float* bl1     = (const float*)d_in[3];
    const float* Wr1     = (const float*)d_in[4];
    const float* Wl2     = (const float*)d_in[5];
    const float* bl2     = (const float*)d_in[6];
    const float* Wr2     = (const float*)d_in[7];
    float* out = (float*)d_out;

    char* ws = (char*)d_ws;
    size_t off = 0;
    auto alloc = [&](size_t bytes) -> void* {
        void* p = ws + off;
        off = (off + bytes + 255) & ~(size_t)255;
        return p;
    };
    unsigned short* xb    = (unsigned short*)alloc((size_t)N_NODES * IN_DIM * 2);  // 51.2 MB
    unsigned short* aggb  = (unsigned short*)alloc((size_t)N_NODES * IN_DIM * 2);  // 51.2 MB
    unsigned short* Wb    = (unsigned short*)alloc((size_t)NDIM * KDIM * 2);       // 2 MB
    int* counts           = (int*)alloc((size_t)(N_NODES + 1) * 4);
    int* offs             = (int*)alloc((size_t)(N_NODES + 1) * 4);
    int* cursor           = (int*)alloc((size_t)N_NODES * 4);
    int* bucket           = (int*)alloc((size_t)N_EDGES * 4);                      // 3.2 MB
    int* bsums            = (int*)alloc(64 * 4);

    hipMemsetAsync(counts, 0, (size_t)(N_NODES + 1) * 4, stream);

    const int nb = (N_NODES + 1023) / 1024;   // 49

    xconv_kernel<<<(N_NODES * IN_DIM / 4 + 255) / 256, 256, 0, stream>>>(x, xb);
    count_kernel<<<(N_EDGES + 255) / 256, 256, 0, stream>>>(ei, counts);
    scan_local_kernel<<<nb, 1024, 0, stream>>>(counts, offs, bsums, N_NODES);
    scan_bsums_kernel<<<1, 64, 0, stream>>>(bsums, nb);
    scan_apply_kernel<<<nb, 1024, 0, stream>>>(offs, cursor, bsums, counts, N_NODES);
    fill_kernel<<<(N_EDGES + 255) / 256, 256, 0, stream>>>(ei, cursor, bucket);
    aggregate_kernel<<<(N_NODES + 3) / 4, 256, 0, stream>>>(xb, offs, bucket, aggb);
    wconv_kernel<<<(NDIM * KDIM + 255) / 256, 256, 0, stream>>>(Wl1, Wr1, Wl2, Wr2, Wb);

    gemm_kernel<<<NWG, 256, 0, stream>>>(aggb, xb, Wb, bl1, bl2, out);
}